// Round 3
// baseline (1099.351 us; speedup 1.0000x reference)
//
#include <hip/hip_runtime.h>
#include <hip/hip_bf16.h>
#include <cstdint>
#include <cstddef>

// ---------------- types ----------------
typedef __bf16 bf16x8 __attribute__((ext_vector_type(8)));
typedef __bf16 bf16x4 __attribute__((ext_vector_type(4)));
typedef float  f32x4  __attribute__((ext_vector_type(4)));

#define D_MODEL 2048
#define SEQ     4096
#define BATCH   4
#define M_TOK   (BATCH * SEQ)            // 16384 tokens
#define ATTN_SCALE 0.08838834764831845f  // 128^-0.5

#define BM 128
#define BN 128
#define BK 32                            // 64B rows -> 4x16B chunks, XOR swizzle p=c^((r>>1)&3)

#define NSEG   128
#define SEGLEN (SEQ / NSEG)              // 32

// ---------------- helpers ----------------
__device__ __forceinline__ void async_load16(const void* g, void* l) {
    __builtin_amdgcn_global_load_lds(
        (const __attribute__((address_space(1))) unsigned int*)g,
        (__attribute__((address_space(3))) unsigned int*)l,
        16, 0, 0);
}
__device__ __forceinline__ int swz(int r) { return (r >> 1) & 3; }

// ---------------- cast fp32 -> bf16 (8 elems / thread) ----------------
__global__ __launch_bounds__(256) void k_cast_bf16(const float* __restrict__ in,
                                                   __bf16* __restrict__ out,
                                                   int n8) {
    int i = blockIdx.x * 256 + threadIdx.x;
    if (i >= n8) return;
    const float4* in4 = (const float4*)in;
    float4 a = in4[2 * i];
    float4 b = in4[2 * i + 1];
    bf16x8 o;
    o[0] = (__bf16)a.x; o[1] = (__bf16)a.y; o[2] = (__bf16)a.z; o[3] = (__bf16)a.w;
    o[4] = (__bf16)b.x; o[5] = (__bf16)b.y; o[6] = (__bf16)b.z; o[7] = (__bf16)b.w;
    ((bf16x8*)out)[i] = o;
}

__global__ __launch_bounds__(256) void k_cast_w4(const float* __restrict__ w0,
                                                 const float* __restrict__ w1,
                                                 const float* __restrict__ w2,
                                                 const float* __restrict__ w3,
                                                 __bf16* __restrict__ out, int n8) {
    const float* srcs[4] = {w0, w1, w2, w3};
    const float* in = srcs[blockIdx.y];
    __bf16* o = out + (size_t)blockIdx.y * (size_t)n8 * 8;
    int i = blockIdx.x * 256 + threadIdx.x;
    if (i >= n8) return;
    const float4* in4 = (const float4*)in;
    float4 a = in4[2 * i];
    float4 b = in4[2 * i + 1];
    bf16x8 v;
    v[0] = (__bf16)a.x; v[1] = (__bf16)a.y; v[2] = (__bf16)a.z; v[3] = (__bf16)a.w;
    v[4] = (__bf16)b.x; v[5] = (__bf16)b.y; v[6] = (__bf16)b.z; v[7] = (__bf16)b.w;
    ((bf16x8*)o)[i] = v;
}

// ---------------- fused QKV GEMM: shared A-tile, 3 outputs ----------------
// 768 threads = 12 waves; wave w: z = w>>2 (0=q,1=k,2=v), quad = w&3 (2x2 of 64x64).
// LDS: As[128x32] + Bs[3][128x32], 32 KB, XOR-swizzled chunks for conflict-free b128 reads.
__global__ __launch_bounds__(768, 4) void k_gemm_qkv(
    const __bf16* __restrict__ A,
    const __bf16* __restrict__ wq, const __bf16* __restrict__ wk, const __bf16* __restrict__ wv,
    const float* __restrict__ bq, const float* __restrict__ bk, const float* __restrict__ bv,
    __bf16* __restrict__ oq, __bf16* __restrict__ ok, __bf16* __restrict__ ov) {
    __shared__ __align__(16) __bf16 As[BM * BK];        // 4096 elems
    __shared__ __align__(16) __bf16 Bs[3 * BN * BK];    // 12288 elems

    const int tid  = threadIdx.x;
    const int lane = tid & 63;
    const int wave = tid >> 6;
    const int zw   = wave >> 2;          // this wave's output
    const int quad = wave & 3;
    const int waveM = quad & 1;
    const int waveN = quad >> 1;
    const long bm = (long)blockIdx.y * BM;
    const long bn = (long)blockIdx.x * BN;
    const int K = D_MODEL, N = D_MODEL;

    // ---- staging setup ----
    // A: threads 0..511 load chunk t (row t>>2, phys chunk t&3)
    const int ar = tid >> 2, apc = tid & 3;
    const __bf16* gA = A + (bm + ar) * (long)K + (long)((apc ^ swz(ar)) * 8);
    __bf16* lA = As + tid * 8;
    // B: every thread loads chunks cb0=tid, cb1=tid+768 of the 1536 (3 z x 512)
    const __bf16* gB[2]; __bf16* lB[2];
#pragma unroll
    for (int u = 0; u < 2; u++) {
        int cb = tid + u * 768;
        int z  = cb >> 9;
        int w  = cb & 511;
        int r  = w >> 2, pc = w & 3;
        const __bf16* Wz = (z == 0) ? wq : (z == 1) ? wk : wv;
        gB[u] = Wz + (bn + r) * (long)K + (long)((pc ^ swz(r)) * 8);
        lB[u] = Bs + cb * 8;
    }

    // ---- fragment LDS offsets (elems), hoisted out of k-loop ----
    const int ksel = lane >> 4;          // 0..3
    int offA[4], offB[4];
#pragma unroll
    for (int i = 0; i < 4; i++) {
        int r = waveM * 64 + (lane & 15) + 16 * i;
        offA[i] = r * BK + (ksel ^ swz(r)) * 8;
    }
#pragma unroll
    for (int j = 0; j < 4; j++) {
        int r = waveN * 64 + (lane & 15) + 16 * j;
        offB[j] = zw * (BN * BK) + r * BK + (ksel ^ swz(r)) * 8;
    }

    f32x4 acc[4][4] = {};

    for (int k0 = 0; k0 < K; k0 += BK) {
        if (tid < 512) async_load16(gA + k0, lA);
        async_load16(gB[0] + k0, lB[0]);
        async_load16(gB[1] + k0, lB[1]);
        __syncthreads();

        bf16x8 af[4], bfr[4];
#pragma unroll
        for (int i = 0; i < 4; i++) af[i]  = *(const bf16x8*)(As + offA[i]);
#pragma unroll
        for (int j = 0; j < 4; j++) bfr[j] = *(const bf16x8*)(Bs + offB[j]);
#pragma unroll
        for (int i = 0; i < 4; i++)
#pragma unroll
            for (int j = 0; j < 4; j++)
                acc[i][j] = __builtin_amdgcn_mfma_f32_16x16x32_bf16(
                    af[i], bfr[j], acc[i][j], 0, 0, 0);
        __syncthreads();
    }

    // ---- epilogue ----
    const float* bias = (zw == 0) ? bq : (zw == 1) ? bk : bv;
    __bf16*      Co   = (zw == 0) ? oq : (zw == 1) ? ok : ov;
    const int r0 = (lane >> 4) * 4;
    const int cn = lane & 15;
#pragma unroll
    for (int i = 0; i < 4; i++) {
        long mg = bm + waveM * 64 + i * 16 + r0;
#pragma unroll
        for (int j = 0; j < 4; j++) {
            long ng = bn + waveN * 64 + j * 16 + cn;
            float bia = bias[ng];
#pragma unroll
            for (int r = 0; r < 4; r++) {
                float v = acc[i][j][r] + bia;
                if (zw < 2) v = (v > 0.f) ? (v + 1.f) : __expf(v);   // phi = elu+1
                Co[(mg + r) * (long)N + ng] = (__bf16)v;
            }
        }
    }
}

// ---------------- out GEMM: C = ctx * Wo^T + bo (fp32 out) ----------------
__global__ __launch_bounds__(256, 4) void k_gemm_out(
    const __bf16* __restrict__ A, const __bf16* __restrict__ Bm,
    const float* __restrict__ bias, float* __restrict__ C) {
    __shared__ __align__(16) __bf16 As[BM * BK];
    __shared__ __align__(16) __bf16 Bs[BN * BK];

    const int tid  = threadIdx.x;
    const int lane = tid & 63;
    const int wave = tid >> 6;
    const int waveM = wave & 1;
    const int waveN = wave >> 1;
    const long bm = (long)blockIdx.y * BM;
    const long bn = (long)blockIdx.x * BN;
    const int K = D_MODEL, N = D_MODEL;

    // staging: thread t loads A-chunks {t, t+256} and B-chunks {t, t+256}
    const __bf16* gA[2]; const __bf16* gB[2]; __bf16* lA[2]; __bf16* lB[2];
#pragma unroll
    for (int u = 0; u < 2; u++) {
        int c = tid + u * 256;
        int r = c >> 2, pc = c & 3;
        int co = (pc ^ swz(r)) * 8;
        gA[u] = A  + (bm + r) * (long)K + co;
        gB[u] = Bm + (bn + r) * (long)K + co;
        lA[u] = As + c * 8;
        lB[u] = Bs + c * 8;
    }

    const int ksel = lane >> 4;
    int offA[4], offB[4];
#pragma unroll
    for (int i = 0; i < 4; i++) {
        int r = waveM * 64 + (lane & 15) + 16 * i;
        offA[i] = r * BK + (ksel ^ swz(r)) * 8;
    }
#pragma unroll
    for (int j = 0; j < 4; j++) {
        int r = waveN * 64 + (lane & 15) + 16 * j;
        offB[j] = r * BK + (ksel ^ swz(r)) * 8;
    }

    f32x4 acc[4][4] = {};

    for (int k0 = 0; k0 < K; k0 += BK) {
#pragma unroll
        for (int u = 0; u < 2; u++) { async_load16(gA[u] + k0, lA[u]); }
#pragma unroll
        for (int u = 0; u < 2; u++) { async_load16(gB[u] + k0, lB[u]); }
        __syncthreads();

        bf16x8 af[4], bfr[4];
#pragma unroll
        for (int i = 0; i < 4; i++) af[i]  = *(const bf16x8*)(As + offA[i]);
#pragma unroll
        for (int j = 0; j < 4; j++) bfr[j] = *(const bf16x8*)(Bs + offB[j]);
#pragma unroll
        for (int i = 0; i < 4; i++)
#pragma unroll
            for (int j = 0; j < 4; j++)
                acc[i][j] = __builtin_amdgcn_mfma_f32_16x16x32_bf16(
                    af[i], bfr[j], acc[i][j], 0, 0, 0);
        __syncthreads();
    }

    const int r0 = (lane >> 4) * 4;
    const int cn = lane & 15;
#pragma unroll
    for (int i = 0; i < 4; i++) {
        long mg = bm + waveM * 64 + i * 16 + r0;
#pragma unroll
        for (int j = 0; j < 4; j++) {
            long ng = bn + waveN * 64 + j * 16 + cn;
            float bia = bias[ng];
#pragma unroll
            for (int r = 0; r < 4; r++)
                C[(mg + r) * (long)N + ng] = acc[i][j][r] + bia;
        }
    }
}

// ---------------- scan pass 1: per-segment sums of phi_k * v ----------------
__global__ __launch_bounds__(256) void k_scan_partial(
    const __bf16* __restrict__ phik, const __bf16* __restrict__ v,
    float* __restrict__ partial) {
    const int b  = blockIdx.z;
    const int s  = blockIdx.y;
    const int c0 = blockIdx.x * 1024 + threadIdx.x * 4;
    long base = ((long)b * SEQ + (long)s * SEGLEN) * D_MODEL + c0;
    const bf16x4* pk = (const bf16x4*)(phik + base);
    const bf16x4* pv = (const bf16x4*)(v + base);
    float s0 = 0, s1 = 0, s2 = 0, s3 = 0;
    for (int l = 0; l < SEGLEN; l++) {
        bf16x4 a = *pk, w = *pv;
        s0 += (float)a[0] * (float)w[0];
        s1 += (float)a[1] * (float)w[1];
        s2 += (float)a[2] * (float)w[2];
        s3 += (float)a[3] * (float)w[3];
        pk += D_MODEL / 4; pv += D_MODEL / 4;
    }
    *(float4*)(partial + ((long)(b * NSEG + s)) * D_MODEL + c0) = make_float4(s0, s1, s2, s3);
}

// ---------------- scan pass 2: running sum + context write (in-place over phik) ----------------
__global__ __launch_bounds__(256) void k_scan_apply(
    const __bf16* __restrict__ phiq,
    __bf16* phik_ctx,
    const __bf16* __restrict__ v,
    const float* __restrict__ partial) {
    const int b  = blockIdx.z;
    const int s  = blockIdx.y;
    const int c0 = blockIdx.x * 1024 + threadIdx.x * 4;
    float r0 = 0, r1 = 0, r2 = 0, r3 = 0;
    for (int sp = 0; sp < s; sp++) {
        float4 p = *(const float4*)(partial + ((long)(b * NSEG + sp)) * D_MODEL + c0);
        r0 += p.x; r1 += p.y; r2 += p.z; r3 += p.w;
    }
    long base = ((long)b * SEQ + (long)s * SEGLEN) * D_MODEL + c0;
    bf16x4* pk = (bf16x4*)(phik_ctx + base);
    const bf16x4* pv = (const bf16x4*)(v + base);
    const bf16x4* pq = (const bf16x4*)(phiq + base);
    for (int l = 0; l < SEGLEN; l++) {
        bf16x4 a = *pk, w = *pv, q = *pq;
        r0 += (float)a[0] * (float)w[0];
        r1 += (float)a[1] * (float)w[1];
        r2 += (float)a[2] * (float)w[2];
        r3 += (float)a[3] * (float)w[3];
        bf16x4 o;
        o[0] = (__bf16)((float)q[0] * r0 * ATTN_SCALE);
        o[1] = (__bf16)((float)q[1] * r1 * ATTN_SCALE);
        o[2] = (__bf16)((float)q[2] * r2 * ATTN_SCALE);
        o[3] = (__bf16)((float)q[3] * r3 * ATTN_SCALE);
        *pk = o;
        pk += D_MODEL / 4; pv += D_MODEL / 4; pq += D_MODEL / 4;
    }
}

// ---------------- launch ----------------
extern "C" void kernel_launch(void* const* d_in, const int* in_sizes, int n_in,
                              void* d_out, int out_size, void* d_ws, size_t ws_size,
                              hipStream_t stream) {
    const float* x  = (const float*)d_in[0];
    const float* Wq = (const float*)d_in[1];
    const float* bq = (const float*)d_in[2];
    const float* Wk = (const float*)d_in[3];
    const float* bk = (const float*)d_in[4];
    const float* Wv = (const float*)d_in[5];
    const float* bv = (const float*)d_in[6];
    const float* Wo = (const float*)d_in[7];
    const float* bo = (const float*)d_in[8];

    const size_t XB = (size_t)M_TOK * D_MODEL;
    const size_t WB = (size_t)D_MODEL * D_MODEL;

    char* p = (char*)d_ws;
    __bf16* xb   = (__bf16*)p; p += XB * 2;
    __bf16* wqb  = (__bf16*)p; p += WB * 2;   // wq,wk,wv,wo contiguous
    __bf16* wkb  = (__bf16*)p; p += WB * 2;
    __bf16* wvb  = (__bf16*)p; p += WB * 2;
    __bf16* wob  = (__bf16*)p; p += WB * 2;
    __bf16* phiq = (__bf16*)p; p += XB * 2;
    __bf16* phik = (__bf16*)p; p += XB * 2;
    __bf16* vb   = (__bf16*)p; p += XB * 2;
    if ((size_t)(p - (char*)d_ws) > ws_size) return;

    float*  partial = (float*)xb;  // xb dead after QKV GEMM
    __bf16* ctx     = phik;        // context in-place over phi_k

    // 1) casts
    k_cast_bf16<<<dim3((unsigned)(XB / 8 / 256)), 256, 0, stream>>>(x, xb, (int)(XB / 8));
    k_cast_w4<<<dim3((unsigned)(WB / 8 / 256), 4), 256, 0, stream>>>(Wq, Wk, Wv, Wo, wqb, (int)(WB / 8));

    // 2) fused QKV projection (+phi on q,k), shared A-tile across z
    k_gemm_qkv<<<dim3(D_MODEL / BN, M_TOK / BM), 768, 0, stream>>>(
        xb, wqb, wkb, wvb, bq, bk, bv, phiq, phik, vb);

    // 3) segmented prefix sum of phi_k * v, then context = phi_q * cumsum * scale
    k_scan_partial<<<dim3(2, NSEG, BATCH), 256, 0, stream>>>(phik, vb, partial);
    k_scan_apply<<<dim3(2, NSEG, BATCH), 256, 0, stream>>>(phiq, phik, vb, partial);

    // 4) output projection -> fp32 d_out
    k_gemm_out<<<dim3(D_MODEL / BN, M_TOK / BM), 256, 0, stream>>>(
        ctx, wob, bo, (float*)d_out);
}

// Round 4
// 1052.880 us; speedup vs baseline: 1.0441x; 1.0441x over previous
//
#include <hip/hip_runtime.h>
#include <hip/hip_bf16.h>
#include <cstdint>
#include <cstddef>

// ---------------- types ----------------
typedef __bf16 bf16x8 __attribute__((ext_vector_type(8)));
typedef __bf16 bf16x4 __attribute__((ext_vector_type(4)));
typedef float  f32x4  __attribute__((ext_vector_type(4)));

#define D_MODEL 2048
#define SEQ     4096
#define BATCH   4
#define M_TOK   (BATCH * SEQ)            // 16384 tokens
#define ATTN_SCALE 0.08838834764831845f  // 128^-0.5

#define BM 128
#define BN 128
#define BK 64                            // 128B rows -> 8x16B chunks, XOR swizzle p = c ^ (r&7)

#define NSEG   128
#define SEGLEN (SEQ / NSEG)              // 32

// ---------------- helpers ----------------
__device__ __forceinline__ void async_load16(const void* g, void* l) {
    __builtin_amdgcn_global_load_lds(
        (const __attribute__((address_space(1))) unsigned int*)g,
        (__attribute__((address_space(3))) unsigned int*)l,
        16, 0, 0);
}

// ---------------- single cast kernel: x + 4 weights -> contiguous bf16 ws ----------------
// chunk space: [0, XBc) = x, then 4 weight regions of WBc chunks each. WBc = 2^19.
#define XBc (33554432 / 8)               // 4194304
#define WBc (4194304 / 8)                // 524288 = 2^19
__global__ __launch_bounds__(256) void k_cast_all(
    const float* __restrict__ x,
    const float* __restrict__ w0, const float* __restrict__ w1,
    const float* __restrict__ w2, const float* __restrict__ w3,
    __bf16* __restrict__ out) {
    size_t i = (size_t)blockIdx.x * 256 + threadIdx.x;   // chunk id (8 elems)
    const float* src;
    size_t off;
    if (i < XBc) { src = x; off = i; }
    else {
        size_t j = i - XBc;
        int w = (int)(j >> 19);
        off = j & (WBc - 1);
        src = (w == 0) ? w0 : (w == 1) ? w1 : (w == 2) ? w2 : w3;
    }
    const float4* in4 = (const float4*)src;
    float4 a = in4[2 * off];
    float4 b = in4[2 * off + 1];
    bf16x8 o;
    o[0] = (__bf16)a.x; o[1] = (__bf16)a.y; o[2] = (__bf16)a.z; o[3] = (__bf16)a.w;
    o[4] = (__bf16)b.x; o[5] = (__bf16)b.y; o[6] = (__bf16)b.z; o[7] = (__bf16)b.w;
    ((bf16x8*)out)[i] = o;
}

// ---------------- QKV GEMM: C = A * W^T + b, phi on q/k ----------------
// 1-D grid 6144 = 128 stripes x 48 (16 n-tiles x 3 z). XCD-aware: xcd = flat&7;
// each XCD owns stripes {xcd, xcd+8, ...}; a stripe's 48 blocks are consecutive
// on that XCD so its 512 KB A-stripe lives in the XCD L2 and is fetched once.
__global__ __launch_bounds__(256) void k_gemm_qkv(
    const __bf16* __restrict__ A,
    const __bf16* __restrict__ wq, const __bf16* __restrict__ wk, const __bf16* __restrict__ wv,
    const float* __restrict__ bq, const float* __restrict__ bk, const float* __restrict__ bv,
    __bf16* __restrict__ oq, __bf16* __restrict__ ok, __bf16* __restrict__ ov) {
    __shared__ __align__(16) __bf16 As[BM * BK];   // 16 KB
    __shared__ __align__(16) __bf16 Bs[BN * BK];   // 16 KB

    const int flat   = blockIdx.x;
    const int xcd    = flat & 7;
    const int local  = flat >> 3;                 // 0..767
    const int stripe = xcd + 8 * (local / 48);    // 0..127 (m-stripe)
    const int within = local % 48;
    const int nblk   = within & 15;
    const int z      = within >> 4;               // 0=q 1=k 2=v

    const __bf16* Bm   = (z == 0) ? wq : (z == 1) ? wk : wv;
    const float*  bias = (z == 0) ? bq : (z == 1) ? bk : bv;
    __bf16*       Co   = (z == 0) ? oq : (z == 1) ? ok : ov;

    const int tid  = threadIdx.x;
    const int lane = tid & 63;
    const int wave = tid >> 6;
    const int waveM = wave & 1;
    const int waveN = wave >> 1;
    const long bm = (long)stripe * BM;
    const long bn = (long)nblk * BN;
    const int K = D_MODEL, N = D_MODEL;

    // staging: 4 chunks per matrix per thread; chunk c = q*256+t -> row c>>3, phys c&7
    const __bf16* gA[4]; const __bf16* gB[4]; __bf16* lA[4]; __bf16* lB[4];
#pragma unroll
    for (int q = 0; q < 4; q++) {
        int c = q * 256 + tid;
        int r = c >> 3, pc = c & 7;
        long co = (long)((pc ^ (r & 7)) * 8);
        gA[q] = A  + (bm + r) * (long)K + co;
        gB[q] = Bm + (bn + r) * (long)K + co;
        lA[q] = As + c * 8;
        lB[q] = Bs + c * 8;
    }

    // hoisted fragment offsets (elems): row r, logical chunk L = s*4+ksel, phys = L^(r&7)
    const int ksel = lane >> 4;
    int offA[2][4], offB[2][4];
#pragma unroll
    for (int s = 0; s < 2; s++) {
#pragma unroll
        for (int i = 0; i < 4; i++) {
            int rA = waveM * 64 + (lane & 15) + 16 * i;
            int rB = waveN * 64 + (lane & 15) + 16 * i;
            offA[s][i] = rA * BK + (((s * 4 + ksel) ^ (rA & 7)) * 8);
            offB[s][i] = rB * BK + (((s * 4 + ksel) ^ (rB & 7)) * 8);
        }
    }

    f32x4 acc[4][4] = {};

    for (int k0 = 0; k0 < K; k0 += BK) {
#pragma unroll
        for (int q = 0; q < 4; q++) async_load16(gA[q] + k0, lA[q]);
#pragma unroll
        for (int q = 0; q < 4; q++) async_load16(gB[q] + k0, lB[q]);
        __syncthreads();

#pragma unroll
        for (int s = 0; s < 2; s++) {
            bf16x8 af[4], bfr[4];
#pragma unroll
            for (int i = 0; i < 4; i++) af[i]  = *(const bf16x8*)(As + offA[s][i]);
#pragma unroll
            for (int j = 0; j < 4; j++) bfr[j] = *(const bf16x8*)(Bs + offB[s][j]);
#pragma unroll
            for (int i = 0; i < 4; i++)
#pragma unroll
                for (int j = 0; j < 4; j++)
                    acc[i][j] = __builtin_amdgcn_mfma_f32_16x16x32_bf16(
                        af[i], bfr[j], acc[i][j], 0, 0, 0);
        }
        __syncthreads();
    }

    const int r0 = (lane >> 4) * 4;
    const int cn = lane & 15;
#pragma unroll
    for (int i = 0; i < 4; i++) {
        long mg = bm + waveM * 64 + i * 16 + r0;
#pragma unroll
        for (int j = 0; j < 4; j++) {
            long ng = bn + waveN * 64 + j * 16 + cn;
            float bia = bias[ng];
#pragma unroll
            for (int r = 0; r < 4; r++) {
                float v = acc[i][j][r] + bia;
                if (z < 2) v = (v > 0.f) ? (v + 1.f) : __expf(v);   // phi = elu+1
                Co[(mg + r) * (long)N + ng] = (__bf16)v;
            }
        }
    }
}

// ---------------- out GEMM: C = ctx * Wo^T + bo (fp32 out) ----------------
// 1-D grid 2048 = 128 stripes x 16 n-tiles, XCD-swizzled like QKV.
__global__ __launch_bounds__(256) void k_gemm_out(
    const __bf16* __restrict__ A, const __bf16* __restrict__ Bm,
    const float* __restrict__ bias, float* __restrict__ C) {
    __shared__ __align__(16) __bf16 As[BM * BK];
    __shared__ __align__(16) __bf16 Bs[BN * BK];

    const int flat   = blockIdx.x;
    const int xcd    = flat & 7;
    const int local  = flat >> 3;                 // 0..255
    const int stripe = xcd + 8 * (local >> 4);    // 0..127
    const int nblk   = local & 15;

    const int tid  = threadIdx.x;
    const int lane = tid & 63;
    const int wave = tid >> 6;
    const int waveM = wave & 1;
    const int waveN = wave >> 1;
    const long bm = (long)stripe * BM;
    const long bn = (long)nblk * BN;
    const int K = D_MODEL, N = D_MODEL;

    const __bf16* gA[4]; const __bf16* gB[4]; __bf16* lA[4]; __bf16* lB[4];
#pragma unroll
    for (int q = 0; q < 4; q++) {
        int c = q * 256 + tid;
        int r = c >> 3, pc = c & 7;
        long co = (long)((pc ^ (r & 7)) * 8);
        gA[q] = A  + (bm + r) * (long)K + co;
        gB[q] = Bm + (bn + r) * (long)K + co;
        lA[q] = As + c * 8;
        lB[q] = Bs + c * 8;
    }

    const int ksel = lane >> 4;
    int offA[2][4], offB[2][4];
#pragma unroll
    for (int s = 0; s < 2; s++) {
#pragma unroll
        for (int i = 0; i < 4; i++) {
            int rA = waveM * 64 + (lane & 15) + 16 * i;
            int rB = waveN * 64 + (lane & 15) + 16 * i;
            offA[s][i] = rA * BK + (((s * 4 + ksel) ^ (rA & 7)) * 8);
            offB[s][i] = rB * BK + (((s * 4 + ksel) ^ (rB & 7)) * 8);
        }
    }

    f32x4 acc[4][4] = {};

    for (int k0 = 0; k0 < K; k0 += BK) {
#pragma unroll
        for (int q = 0; q < 4; q++) async_load16(gA[q] + k0, lA[q]);
#pragma unroll
        for (int q = 0; q < 4; q++) async_load16(gB[q] + k0, lB[q]);
        __syncthreads();

#pragma unroll
        for (int s = 0; s < 2; s++) {
            bf16x8 af[4], bfr[4];
#pragma unroll
            for (int i = 0; i < 4; i++) af[i]  = *(const bf16x8*)(As + offA[s][i]);
#pragma unroll
            for (int j = 0; j < 4; j++) bfr[j] = *(const bf16x8*)(Bs + offB[s][j]);
#pragma unroll
            for (int i = 0; i < 4; i++)
#pragma unroll
                for (int j = 0; j < 4; j++)
                    acc[i][j] = __builtin_amdgcn_mfma_f32_16x16x32_bf16(
                        af[i], bfr[j], acc[i][j], 0, 0, 0);
        }
        __syncthreads();
    }

    const int r0 = (lane >> 4) * 4;
    const int cn = lane & 15;
#pragma unroll
    for (int i = 0; i < 4; i++) {
        long mg = bm + waveM * 64 + i * 16 + r0;
#pragma unroll
        for (int j = 0; j < 4; j++) {
            long ng = bn + waveN * 64 + j * 16 + cn;
            float bia = bias[ng];
#pragma unroll
            for (int r = 0; r < 4; r++)
                C[(mg + r) * (long)N + ng] = acc[i][j][r] + bia;
        }
    }
}

// ---------------- scan pass 1: per-segment sums of phi_k * v (8 ch/thread) ----------------
__global__ __launch_bounds__(256) void k_scan_partial(
    const __bf16* __restrict__ phik, const __bf16* __restrict__ v,
    float* __restrict__ partial) {
    const int b  = blockIdx.z;
    const int s  = blockIdx.y;
    const int c0 = threadIdx.x * 8;
    long base = ((long)b * SEQ + (long)s * SEGLEN) * D_MODEL + c0;
    const bf16x8* pk = (const bf16x8*)(phik + base);
    const bf16x8* pv = (const bf16x8*)(v + base);
    float acc[8] = {};
    for (int l = 0; l < SEGLEN; l++) {
        bf16x8 a = *pk, w = *pv;
#pragma unroll
        for (int e = 0; e < 8; e++) acc[e] += (float)a[e] * (float)w[e];
        pk += D_MODEL / 8; pv += D_MODEL / 8;
    }
    float* dst = partial + ((long)(b * NSEG + s)) * D_MODEL + c0;
    *(float4*)dst       = make_float4(acc[0], acc[1], acc[2], acc[3]);
    *(float4*)(dst + 4) = make_float4(acc[4], acc[5], acc[6], acc[7]);
}

// ---------------- scan pass 2: running sum + context write (in-place over phik) ----------------
__global__ __launch_bounds__(256) void k_scan_apply(
    const __bf16* __restrict__ phiq,
    __bf16* phik_ctx,
    const __bf16* __restrict__ v,
    const float* __restrict__ partial) {
    const int b  = blockIdx.z;
    const int s  = blockIdx.y;
    const int c0 = threadIdx.x * 8;
    float r[8] = {};
    for (int sp = 0; sp < s; sp++) {
        const float* pp = partial + ((long)(b * NSEG + sp)) * D_MODEL + c0;
        float4 p0 = *(const float4*)pp;
        float4 p1 = *(const float4*)(pp + 4);
        r[0] += p0.x; r[1] += p0.y; r[2] += p0.z; r[3] += p0.w;
        r[4] += p1.x; r[5] += p1.y; r[6] += p1.z; r[7] += p1.w;
    }
    long base = ((long)b * SEQ + (long)s * SEGLEN) * D_MODEL + c0;
    bf16x8* pk = (bf16x8*)(phik_ctx + base);
    const bf16x8* pv = (const bf16x8*)(v + base);
    const bf16x8* pq = (const bf16x8*)(phiq + base);
    for (int l = 0; l < SEGLEN; l++) {
        bf16x8 a = *pk, w = *pv, q = *pq;
        bf16x8 o;
#pragma unroll
        for (int e = 0; e < 8; e++) {
            r[e] += (float)a[e] * (float)w[e];
            o[e] = (__bf16)((float)q[e] * r[e] * ATTN_SCALE);
        }
        *pk = o;
        pk += D_MODEL / 8; pv += D_MODEL / 8; pq += D_MODEL / 8;
    }
}

// ---------------- launch ----------------
extern "C" void kernel_launch(void* const* d_in, const int* in_sizes, int n_in,
                              void* d_out, int out_size, void* d_ws, size_t ws_size,
                              hipStream_t stream) {
    const float* x  = (const float*)d_in[0];
    const float* Wq = (const float*)d_in[1];
    const float* bq = (const float*)d_in[2];
    const float* Wk = (const float*)d_in[3];
    const float* bk = (const float*)d_in[4];
    const float* Wv = (const float*)d_in[5];
    const float* bv = (const float*)d_in[6];
    const float* Wo = (const float*)d_in[7];
    const float* bo = (const float*)d_in[8];

    const size_t XB = (size_t)M_TOK * D_MODEL;
    const size_t WB = (size_t)D_MODEL * D_MODEL;

    char* p = (char*)d_ws;
    __bf16* xb   = (__bf16*)p; p += XB * 2;
    __bf16* wqb  = (__bf16*)p; p += WB * 2;   // wq,wk,wv,wo contiguous after xb
    __bf16* wkb  = (__bf16*)p; p += WB * 2;
    __bf16* wvb  = (__bf16*)p; p += WB * 2;
    __bf16* wob  = (__bf16*)p; p += WB * 2;
    __bf16* phiq = (__bf16*)p; p += XB * 2;
    __bf16* phik = (__bf16*)p; p += XB * 2;
    __bf16* vb   = (__bf16*)p; p += XB * 2;
    if ((size_t)(p - (char*)d_ws) > ws_size) return;

    float*  partial = (float*)xb;  // xb dead after QKV GEMM (4 MB needed)
    __bf16* ctx     = phik;        // context in-place over phi_k

    // 1) one cast kernel: x + 4 weights
    k_cast_all<<<dim3((unsigned)((XBc + 4 * WBc) / 256)), 256, 0, stream>>>(
        x, Wq, Wk, Wv, Wo, xb);

    // 2) QKV projection (+phi on q,k), XCD-swizzled 1-D grid
    k_gemm_qkv<<<dim3(128 * 48), 256, 0, stream>>>(
        xb, wqb, wkb, wvb, bq, bk, bv, phiq, phik, vb);

    // 3) segmented prefix sum of phi_k * v, then context = phi_q * cumsum * scale
    k_scan_partial<<<dim3(1, NSEG, BATCH), 256, 0, stream>>>(phik, vb, partial);
    k_scan_apply<<<dim3(1, NSEG, BATCH), 256, 0, stream>>>(phiq, phik, vb, partial);

    // 4) output projection -> fp32 d_out
    k_gemm_out<<<dim3(128 * 16), 256, 0, stream>>>(
        ctx, wob, bo, (float*)d_out);
}